// Round 2
// baseline (627.215 us; speedup 1.0000x reference)
//
#include <hip/hip_runtime.h>
#include <math.h>

#define NN 100000
#define NE 3200000
#define INC 128
#define HID 16
#define OC 40
#define NCHUNK 98  // ceil(NN/1024)

__global__ void k_zero_i(int* __restrict__ p, int n) {
    int i = blockIdx.x * blockDim.x + threadIdx.x;
    if (i < n) p[i] = 0;
}

// deg[d] = #in-edges (self-loop accounted as +1 later)
__global__ void k_deg(const int* __restrict__ dst, int* __restrict__ deg) {
    int e = blockIdx.x * blockDim.x + threadIdx.x;
    if (e < NE) {
        unsigned d = (unsigned)dst[e];
        if (d < NN) atomicAdd(&deg[d], 1);
    }
}

// chunk-local exclusive scan of deg -> off, chunk totals -> bsum
__global__ __launch_bounds__(1024) void k_scan1(const int* __restrict__ deg,
                                                int* __restrict__ off,
                                                int* __restrict__ bsum) {
    __shared__ int s[1024];
    int t = threadIdx.x;
    int i = blockIdx.x * 1024 + t;
    int v = (i < NN) ? deg[i] : 0;
    s[t] = v;
    __syncthreads();
    for (int d = 1; d < 1024; d <<= 1) {
        int add = (t >= d) ? s[t - d] : 0;
        __syncthreads();
        s[t] += add;
        __syncthreads();
    }
    if (i < NN) off[i] = s[t] - v;           // exclusive within chunk
    if (t == 1023) bsum[blockIdx.x] = s[1023];
}

// exclusive scan of the 98 chunk totals
__global__ void k_scan2(const int* __restrict__ bsum, int* __restrict__ bo) {
    __shared__ int s[128];
    int t = threadIdx.x;
    int v = (t < NCHUNK) ? bsum[t] : 0;
    s[t] = v;
    __syncthreads();
    for (int d = 1; d < 128; d <<= 1) {
        int add = (t >= d) ? s[t - d] : 0;
        __syncthreads();
        s[t] += add;
        __syncthreads();
    }
    if (t < NCHUNK) bo[t] = s[t] - v;
}

// finalize offsets, init cursor, compute dis = rsqrt(deg+1)
__global__ void k_scan3(int* __restrict__ off, const int* __restrict__ bo,
                        int* __restrict__ cursor, const int* __restrict__ deg,
                        float* __restrict__ dis) {
    int i = blockIdx.x * blockDim.x + threadIdx.x;
    if (i < NN) {
        int o = off[i] + bo[i >> 10];
        off[i] = o;
        cursor[i] = o;
        dis[i] = rsqrtf((float)(deg[i] + 1));
    }
    if (i == 0) off[NN] = NE;
}

// counting-sort fill: csr_src[pos] = src[e], bucketed by dst
__global__ void k_fill(const int* __restrict__ src, const int* __restrict__ dst,
                       int* __restrict__ cursor, int* __restrict__ csr_src) {
    int e = blockIdx.x * blockDim.x + threadIdx.x;
    if (e < NE) {
        unsigned d = (unsigned)dst[e];
        unsigned s = (unsigned)src[e];
        if (d < NN && s < NN) {
            int p = atomicAdd(&cursor[d], 1);
            csr_src[p] = (int)s;
        }
    }
}

// h1 = x @ W1 : [NN,128] @ [128,16] -> [NN,16]
__global__ __launch_bounds__(256) void k_gemm1(const float* __restrict__ x,
                                               const float* __restrict__ W1,
                                               float* __restrict__ h1) {
    __shared__ float xs[16][INC + 1];
    __shared__ float ws[INC][HID];
    int t = threadIdx.x;
    int rowbase = blockIdx.x * 16;  // NN/16 = 6250 exact
#pragma unroll
    for (int i = 0; i < 8; ++i) {
        int idx = t + i * 256;
        xs[idx >> 7][idx & 127] = x[(long long)(rowbase)*INC + idx];
    }
#pragma unroll
    for (int i = 0; i < 8; ++i) {
        int idx = t + i * 256;
        ws[idx >> 4][idx & 15] = W1[idx];
    }
    __syncthreads();
    int r = t >> 4, c = t & 15;
    float acc = 0.f;
#pragma unroll
    for (int k = 0; k < INC; ++k) acc += xs[r][k] * ws[k][c];
    h1[(rowbase + r) * HID + c] = acc;
}

// out[i][c] = (relu? max(0, b[c] + A) : A),  A = dis_i^2*hin[i][c] + sum_s dis_s*dis_i*hin[s][c]
// 16 threads per node, 16 nodes per block
__global__ __launch_bounds__(256) void k_gather(const float* __restrict__ hin,
                                                const float* __restrict__ dis,
                                                const int* __restrict__ off,
                                                const int* __restrict__ csr_src,
                                                const float* __restrict__ b,
                                                float* __restrict__ outp, int relu) {
    int t = threadIdx.x;
    int node = blockIdx.x * 16 + (t >> 4);
    int c = t & 15;
    if (node >= NN) return;
    float di = dis[node];
    int beg = off[node], end = off[node + 1];
    float acc = di * di * hin[node * HID + c];
    int j = beg;
    for (; j + 1 < end; j += 2) {
        int s0 = csr_src[j], s1 = csr_src[j + 1];
        float n0 = dis[s0], n1 = dis[s1];
        acc += di * n0 * hin[s0 * HID + c];
        acc += di * n1 * hin[s1 * HID + c];
    }
    if (j < end) {
        int s0 = csr_src[j];
        acc += di * dis[s0] * hin[s0 * HID + c];
    }
    if (relu) acc = fmaxf(acc + b[c], 0.f);
    outp[node * HID + c] = acc;
}

// out[i] = log_softmax(agg2[i] @ W2 + b2)
__global__ __launch_bounds__(256) void k_final(const float* __restrict__ agg2,
                                               const float* __restrict__ W2,
                                               const float* __restrict__ b2,
                                               float* __restrict__ out) {
    __shared__ float w2s[HID * OC];
    __shared__ float b2s[OC];
    int t = threadIdx.x;
    for (int i = t; i < HID * OC; i += 256) w2s[i] = W2[i];
    if (t < OC) b2s[t] = b2[t];
    __syncthreads();
    int row = blockIdx.x * 256 + t;
    if (row >= NN) return;
    float a[HID];
#pragma unroll
    for (int k = 0; k < HID; ++k) a[k] = agg2[row * HID + k];
    float z[OC];
#pragma unroll
    for (int c = 0; c < OC; ++c) z[c] = b2s[c];
#pragma unroll
    for (int k = 0; k < HID; ++k) {
        float av = a[k];
#pragma unroll
        for (int c = 0; c < OC; ++c) z[c] += av * w2s[k * OC + c];
    }
    float m = z[0];
#pragma unroll
    for (int c = 1; c < OC; ++c) m = fmaxf(m, z[c]);
    float ssum = 0.f;
#pragma unroll
    for (int c = 0; c < OC; ++c) ssum += expf(z[c] - m);
    float lse = m + logf(ssum);
#pragma unroll
    for (int c = 0; c < OC; ++c) out[row * OC + c] = z[c] - lse;
}

extern "C" void kernel_launch(void* const* d_in, const int* in_sizes, int n_in,
                              void* d_out, int out_size, void* d_ws, size_t ws_size,
                              hipStream_t stream) {
    const float* x  = (const float*)d_in[0];
    const int*   ei = (const int*)d_in[1];
    const float* W1 = (const float*)d_in[2];
    const float* b1 = (const float*)d_in[3];
    const float* W2 = (const float*)d_in[4];
    const float* b2 = (const float*)d_in[5];
    float* out = (float*)d_out;

    const int* src = ei;       // edge_index[0]
    const int* dst = ei + NE;  // edge_index[1]

    char* ws = (char*)d_ws;
    size_t o = 0;
    int*   deg    = (int*)(ws + o);  o += (size_t)NN * 4;
    int*   off    = (int*)(ws + o);  o += (size_t)(NN + 1) * 4;
    int*   cursor = (int*)(ws + o);  o += (size_t)NN * 4;
    float* dis    = (float*)(ws + o); o += (size_t)NN * 4;
    int*   bsum   = (int*)(ws + o);  o += 128 * 4;
    int*   bo     = (int*)(ws + o);  o += 128 * 4;
    int*   csr    = (int*)(ws + o);  o += (size_t)NE * 4;
    float* bufA   = (float*)(ws + o); o += (size_t)NN * HID * 4;
    float* bufB   = (float*)(ws + o); o += (size_t)NN * HID * 4;
    // total ~27.3MB

    dim3 B(256);
    int gN = (NN + 255) / 256;
    int gE = (NE + 255) / 256;

    k_zero_i<<<gN, B, 0, stream>>>(deg, NN);
    k_deg<<<gE, B, 0, stream>>>(dst, deg);
    k_scan1<<<NCHUNK, 1024, 0, stream>>>(deg, off, bsum);
    k_scan2<<<1, 128, 0, stream>>>(bsum, bo);
    k_scan3<<<gN, B, 0, stream>>>(off, bo, cursor, deg, dis);
    k_fill<<<gE, B, 0, stream>>>(src, dst, cursor, csr);
    k_gemm1<<<NN / 16, B, 0, stream>>>(x, W1, bufA);
    k_gather<<<NN / 16, B, 0, stream>>>(bufA, dis, off, csr, b1, bufB, 1);
    k_gather<<<NN / 16, B, 0, stream>>>(bufB, dis, off, csr, b1, bufA, 0);
    k_final<<<gN, B, 0, stream>>>(bufA, W2, b2, out);
}